// Round 15
// baseline (756.671 us; speedup 1.0000x reference)
//
#include <hip/hip_runtime.h>
#include <stdint.h>

// ============================================================================
// CPC forward on MI355X (gfx950).
// R2-R14: W_hh register residency unachievable at f16 size; GRU is bound by
// the per-CU L1<->L2 fill rate (~128B/cyc): 384KB/step -> 3072cyc -> 316us.
// Coalescing the stream (R14) was worth only 3% -> byte count is the lever.
// R15: W_hh as fp8 e5m2 = TOP BYTE of f16 (RTN at prep). Dequant ~free:
//   lo_pair = v_pk_lshlrev_b16(x,8)  (bytes 0,2 -> two f16)
//   hi_pair = x & 0xFF00FF00         (bytes 1,3 -> two f16)
// (bytes interleaved at prep so pairs match h pairs). L2 192KB/step = 1536
// cyc; VALU ~1600 cyc -> ~180-210us. W/thread = 64 regs: may even go
// register-resident. Precision: e5m2 RTN ~3.6% RMS/weight -> ~0.2% dot err
// -> c_seq drift ~1e-3..1e-2 vs ~0.03 threshold.
// ============================================================================

typedef _Float16 f16;
typedef __attribute__((ext_vector_type(2))) _Float16 f16x2;
typedef __attribute__((ext_vector_type(8))) _Float16 f16x8;
typedef __attribute__((ext_vector_type(4))) float f32x4;

__device__ __forceinline__ f16x2 u2h(unsigned int x) { return __builtin_bit_cast(f16x2, x); }
__device__ __forceinline__ float sigm_(float x) { return __builtin_amdgcn_rcpf(1.f + __expf(-x)); }
__device__ __forceinline__ float tanh_(float x) { return 1.f - 2.f * __builtin_amdgcn_rcpf(__expf(2.f * x) + 1.f); }
__device__ __forceinline__ uint32_t pksh8(uint32_t x) {
  uint32_t r;
  asm("v_pk_lshlrev_b16 %0, 8, %1" : "=v"(r) : "v"(x));
  return r;
}
// f32 -> e5m2 byte (top byte of f16, round-to-nearest)
__device__ __forceinline__ uint8_t to_bf8(float x) {
  const uint16_t h = __builtin_bit_cast(uint16_t, (f16)x);
  const uint16_t r = (uint16_t)(h + 0x7F + ((h >> 8) & 1));
  return (uint8_t)(r >> 8);
}

#define NTOT_LOSS 374784.0f  // 12 * 128 * 244

// ---------------------------------------------------------------------------
// K0: weight conversion. W_hh -> whh8 fp8 chunk-major:
// whh8[(jq*768+o)*16 + e]: uint4 jq of row o covers k=16jq..16jq+15,
// bytes within each 4-group ordered (k0,k2,k1,k3) so pk_lshl/and dequant
// yields pairs (k0,k1) and (k2,k3) directly.
// ---------------------------------------------------------------------------
__global__ void k_prep(const float* __restrict__ w1, const float* __restrict__ w2,
                       const float* __restrict__ wih, const float* __restrict__ whh,
                       const float* __restrict__ wkw,
                       f16* __restrict__ w1T, f16* __restrict__ w2T, f16* __restrict__ wihF,
                       uint8_t* __restrict__ whh8, f16* __restrict__ wkT, float* __restrict__ accb) {
  const int stride = gridDim.x * blockDim.x;
  const int tid = blockIdx.x * blockDim.x + threadIdx.x;
  if (tid == 0) { accb[0] = 0.f; accb[1] = 0.f; }
  // w1 (256k x 256n) -> w1T[n][k]
  for (int i = tid; i < 65536; i += stride) { int n = i >> 8, k = i & 255; w1T[i] = (f16)w1[k * 256 + n]; }
  // w2 (256k x 128n) -> w2T[n][k]
  for (int i = tid; i < 32768; i += stride) { int n = i >> 8, k = i & 255; w2T[i] = (f16)w2[k * 128 + n]; }
  // W_ih (768 x 128) already [N][K]
  for (int i = tid; i < 98304; i += stride) wihF[i] = (f16)wih[i];
  // W_hh (768 x 256) -> whh8 fp8 chunk-major, byte-interleaved
  for (int idx = tid; idx < 196608; idx += stride) {
    const int e = idx & 15, oo = (idx >> 4) % 768, jq = idx / 12288;
    const int g4 = e >> 2, bo = e & 3;
    const int koff = (bo == 1) ? 2 : (bo == 2) ? 1 : bo;  // 0,2,1,3
    const int k = jq * 16 + g4 * 4 + koff;
    whh8[idx] = to_bf8(whh[oo * 256 + k]);
  }
  // Wk_w (12,256c,128d) -> wkT[kk][d][c]
  for (int i = tid; i < 393216; i += stride) {
    int kk = i >> 15, rem = i & 32767, d = rem >> 8, c = rem & 255;
    wkT[i] = (f16)wkw[(kk << 15) + c * 128 + d];
  }
}

// ---------------------------------------------------------------------------
// Generic 64x64-tile f16 MFMA GEMM (R2 version).
// ---------------------------------------------------------------------------
template <int KTOT, bool AF32, bool RELU>
__global__ __launch_bounds__(256) void k_gemm64(const void* __restrict__ Aptr,
                                                const f16* __restrict__ BT,
                                                const float* __restrict__ bias,
                                                f16* __restrict__ out, const int NT) {
  __shared__ __align__(16) f16 Al[64][40];
  __shared__ __align__(16) f16 Bl[64][40];
  const int m0 = blockIdx.x * 64;
  const int n0 = blockIdx.y * 64;
  const int t = threadIdx.x;
  const int w = t >> 6, l = t & 63, lr = l & 15, lg = l >> 4;
  const int arow = t >> 2, akq = (t & 3) * 8;
  f32x4 acc[4] = {};
  for (int ks = 0; ks < KTOT / 32; ++ks) {
    const int kc = ks * 32;
    __syncthreads();
    if constexpr (AF32) {
      const float* src = (const float*)Aptr + (size_t)(m0 + arow) * KTOT + kc + akq;
      float4 v0 = *(const float4*)src;
      float4 v1 = *(const float4*)(src + 4);
      f16x8 hv = {(f16)v0.x, (f16)v0.y, (f16)v0.z, (f16)v0.w,
                  (f16)v1.x, (f16)v1.y, (f16)v1.z, (f16)v1.w};
      *(f16x8*)&Al[arow][akq] = hv;
    } else {
      const f16* src = (const f16*)Aptr + (size_t)(m0 + arow) * KTOT + kc + akq;
      *(f16x8*)&Al[arow][akq] = *(const f16x8*)src;
    }
    *(f16x8*)&Bl[arow][akq] = *(const f16x8*)(BT + (size_t)(n0 + arow) * KTOT + kc + akq);
    __syncthreads();
    f16x8 af = *(const f16x8*)&Al[16 * w + lr][lg * 8];
#pragma unroll
    for (int nt = 0; nt < 4; ++nt) {
      f16x8 bf = *(const f16x8*)&Bl[nt * 16 + lr][lg * 8];
      acc[nt] = __builtin_amdgcn_mfma_f32_16x16x32_f16(af, bf, acc[nt], 0, 0, 0);
    }
  }
#pragma unroll
  for (int nt = 0; nt < 4; ++nt) {
    const int n = n0 + nt * 16 + lr;
    const float bb = bias[n];
#pragma unroll
    for (int r = 0; r < 4; ++r) {
      const int m = m0 + 16 * w + lg * 4 + r;
      float v = acc[nt][r] + bb;
      if (RELU) v = fmaxf(v, 0.f);
      out[(size_t)m * NT + n] = (f16)v;
    }
  }
}

// ---------------------------------------------------------------------------
// K2: z = l2norm(h1 @ w2T + b2). (R2 version)
// ---------------------------------------------------------------------------
__global__ __launch_bounds__(256) void k_enc2(const f16* __restrict__ A, const f16* __restrict__ BT,
                                              const float* __restrict__ bias,
                                              float* __restrict__ zf32, f16* __restrict__ zf16) {
  __shared__ __align__(16) f16 Al[64][40];
  __shared__ __align__(16) f16 Bl[128][40];
  const int m0 = blockIdx.x * 64;
  const int t = threadIdx.x;
  const int w = t >> 6, l = t & 63, lr = l & 15, lg = l >> 4;
  const int arow = t >> 2, akq = (t & 3) * 8;
  f32x4 acc[8] = {};
  for (int ks = 0; ks < 8; ++ks) {
    const int kc = ks * 32;
    __syncthreads();
    *(f16x8*)&Al[arow][akq] = *(const f16x8*)(A + (size_t)(m0 + arow) * 256 + kc + akq);
#pragma unroll
    for (int hh = 0; hh < 2; ++hh) {
      const int brow = arow + 64 * hh;
      *(f16x8*)&Bl[brow][akq] = *(const f16x8*)(BT + (size_t)brow * 256 + kc + akq);
    }
    __syncthreads();
    f16x8 af = *(const f16x8*)&Al[16 * w + lr][lg * 8];
#pragma unroll
    for (int nt = 0; nt < 8; ++nt) {
      f16x8 bf = *(const f16x8*)&Bl[nt * 16 + lr][lg * 8];
      acc[nt] = __builtin_amdgcn_mfma_f32_16x16x32_f16(af, bf, acc[nt], 0, 0, 0);
    }
  }
  float v[8][4];
#pragma unroll
  for (int nt = 0; nt < 8; ++nt) {
    const float bb = bias[nt * 16 + lr];
#pragma unroll
    for (int r = 0; r < 4; ++r) v[nt][r] = acc[nt][r] + bb;
  }
#pragma unroll
  for (int r = 0; r < 4; ++r) {
    float ss = 0.f;
#pragma unroll
    for (int nt = 0; nt < 8; ++nt) ss += v[nt][r] * v[nt][r];
    ss += __shfl_xor(ss, 1); ss += __shfl_xor(ss, 2); ss += __shfl_xor(ss, 4); ss += __shfl_xor(ss, 8);
    const float scl = 1.f / fmaxf(sqrtf(ss), 1e-12f);
    const int m = m0 + 16 * w + lg * 4 + r;
#pragma unroll
    for (int nt = 0; nt < 8; ++nt) {
      const int n = nt * 16 + lr;
      const float z = v[nt][r] * scl;
      zf32[(size_t)m * 128 + n] = z;
      zf16[(size_t)m * 128 + n] = (f16)z;
    }
  }
}

// ---------------------------------------------------------------------------
// K4: GRU scan, fp8-streamed W. 128 blocks x 768 threads; thread o: gate
// g=o>>8, col c=o&255. W row = 16 uint4 fp8 (64 regs) — streamed or resident
// at the compiler's choice; either way L2 bytes halved vs f16. Dequant:
// pk_lshl(x,8) + and(0xFF00FF00) -> two f16 pairs per u32, fdot2 each.
// ---------------------------------------------------------------------------
__global__ __launch_bounds__(768, 3) void k_gru(const f16* __restrict__ gx, const uint8_t* __restrict__ whh8,
                                                const float* __restrict__ bhh,
                                                float* __restrict__ cout, f16* __restrict__ cf16) {
  __shared__ __align__(16) f16 h_lds[2][256];
  __shared__ float rz[2][256];
  const int b = blockIdx.x;
  const int o = threadIdx.x;
  const int g = o >> 8;
  const int c = o & 255;
  uint4 wv[16];
  {
#pragma unroll
    for (int jq = 0; jq < 16; ++jq)
      wv[jq] = *(const uint4*)(whh8 + ((size_t)jq * 768 + o) * 16);
  }
  const float bh = bhh[o];
  if (o < 256) h_lds[0][o] = (f16)0.f;
  float h_own = 0.f;
  const f16* gxp = gx + (size_t)b * 256 * 768 + o;
  float* coutp = cout + (size_t)b * 256 * 256 + c;
  f16* cfp = cf16 + (size_t)b * 256 * 256 + c;
  __syncthreads();
#pragma unroll 1
  for (int tt = 0; tt < 256; ++tt) {
    const int cur = tt & 1;
    const float gxv = (float)gxp[tt * 768];
    float a0 = 0.f, a1 = 0.f, a2 = 0.f, a3 = 0.f;
    const uint4* hp = (const uint4*)(&h_lds[cur][0]);
#pragma unroll
    for (int jq = 0; jq < 16; ++jq) {
      const uint4 wq = wv[jq];
      const uint4 hA = hp[2 * jq];      // k = 16jq .. +7 (4 f16 pairs)
      const uint4 hB = hp[2 * jq + 1];  // k = 16jq+8 .. +15
      uint32_t lo, hi;
      lo = pksh8(wq.x); hi = wq.x & 0xFF00FF00u;
      a0 = __builtin_amdgcn_fdot2(u2h(lo), u2h(hA.x), a0, false);
      a1 = __builtin_amdgcn_fdot2(u2h(hi), u2h(hA.y), a1, false);
      lo = pksh8(wq.y); hi = wq.y & 0xFF00FF00u;
      a2 = __builtin_amdgcn_fdot2(u2h(lo), u2h(hA.z), a2, false);
      a3 = __builtin_amdgcn_fdot2(u2h(hi), u2h(hA.w), a3, false);
      lo = pksh8(wq.z); hi = wq.z & 0xFF00FF00u;
      a0 = __builtin_amdgcn_fdot2(u2h(lo), u2h(hB.x), a0, false);
      a1 = __builtin_amdgcn_fdot2(u2h(hi), u2h(hB.y), a1, false);
      lo = pksh8(wq.w); hi = wq.w & 0xFF00FF00u;
      a2 = __builtin_amdgcn_fdot2(u2h(lo), u2h(hB.z), a2, false);
      a3 = __builtin_amdgcn_fdot2(u2h(hi), u2h(hB.w), a3, false);
    }
    const float dot = (a0 + a1) + (a2 + a3) + bh;
    if (g < 2) rz[g][c] = sigm_(gxv + dot);
    __syncthreads();
    if (g == 2) {
      const float r = rz[0][c], zz = rz[1][c];
      const float n = tanh_(gxv + r * dot);
      const float hn = (1.f - zz) * n + zz * h_own;
      h_own = hn;
      h_lds[cur ^ 1][c] = (f16)hn;
      coutp[tt * 256] = hn;
      cfp[tt * 256] = (f16)hn;
    }
    __syncthreads();
  }
}

// ---------------------------------------------------------------------------
// K5: fused preds -> l2norm -> logits -> online LSE/pos/negmax -> loss&acc.
// (R2 version: grid (4,128,12), 256 threads, deep block queue.)
// ---------------------------------------------------------------------------
__global__ __launch_bounds__(256) void k_cpc(const f16* __restrict__ cf16, const f16* __restrict__ zf16,
                                             const f16* __restrict__ wkT, const float* __restrict__ wkb,
                                             float* __restrict__ accb) {
  __shared__ __align__(16) f16 SMc[64 * 264];   // c-tile [64][264], reused as z-chunk [64][136]
  __shared__ __align__(16) f16 Bl[128][40];
  __shared__ __align__(16) f16 P[64][136];
  __shared__ float red[2];
  const int tc = blockIdx.x, b = blockIdx.y, kk = blockIdx.z;
  const int t0 = tc * 64;
  const int t = threadIdx.x;
  const int w = t >> 6, l = t & 63, lr = l & 15, lg = l >> 4;
  {
    const uint32_t* src = (const uint32_t*)(cf16 + ((size_t)b * 256 + t0) * 256);
    uint32_t* dst = (uint32_t*)SMc;
#pragma unroll
    for (int it = 0; it < 32; ++it) {
      const int idx = it * 256 + t, row = idx >> 7, cw = idx & 127;
      dst[row * 132 + cw] = src[row * 128 + cw];
    }
  }
  f32x4 acc[8] = {};
  for (int ks = 0; ks < 8; ++ks) {
    __syncthreads();
    {
      const uint32_t* bsrc = (const uint32_t*)(wkT + ((size_t)kk << 15));
      uint32_t* bd = (uint32_t*)Bl;
#pragma unroll
      for (int it = 0; it < 8; ++it) {
        const int idx = it * 256 + t, row = idx >> 4, kw = idx & 15;
        bd[row * 20 + kw] = bsrc[row * 128 + ks * 16 + kw];
      }
    }
    __syncthreads();
    f16x8 af = *(const f16x8*)&SMc[(16 * w + lr) * 264 + ks * 32 + lg * 8];
#pragma unroll
    for (int nt = 0; nt < 8; ++nt) {
      f16x8 bf = *(const f16x8*)&Bl[nt * 16 + lr][lg * 8];
      acc[nt] = __builtin_amdgcn_mfma_f32_16x16x32_f16(af, bf, acc[nt], 0, 0, 0);
    }
  }
  {
    float v[8][4];
#pragma unroll
    for (int nt = 0; nt < 8; ++nt) {
      const float bb = wkb[kk * 128 + nt * 16 + lr];
#pragma unroll
      for (int r = 0; r < 4; ++r) v[nt][r] = acc[nt][r] + bb;
    }
#pragma unroll
    for (int r = 0; r < 4; ++r) {
      float ss = 0.f;
#pragma unroll
      for (int nt = 0; nt < 8; ++nt) ss += v[nt][r] * v[nt][r];
      ss += __shfl_xor(ss, 1); ss += __shfl_xor(ss, 2); ss += __shfl_xor(ss, 4); ss += __shfl_xor(ss, 8);
      const float scl = 1.f / fmaxf(sqrtf(ss), 1e-12f);
#pragma unroll
      for (int nt = 0; nt < 8; ++nt)
        P[16 * w + lg * 4 + r][nt * 16 + lr] = (f16)(v[nt][r] * scl);
    }
  }
  __syncthreads();
  float m_run[4], s_run[4], pos_v[4], neg_m[4];
#pragma unroll
  for (int r = 0; r < 4; ++r) { m_run[r] = -1e30f; s_run[r] = 0.f; pos_v[r] = -1e30f; neg_m[r] = -1e30f; }
  for (int sc = 0; sc < 4; ++sc) {
    __syncthreads();
    {
      const uint32_t* zsrc = (const uint32_t*)(zf16 + ((size_t)b * 256 + sc * 64) * 128);
      uint32_t* zd = (uint32_t*)SMc;
#pragma unroll
      for (int it = 0; it < 16; ++it) {
        const int idx = it * 256 + t, row = idx >> 6, cw = idx & 63;
        zd[row * 68 + cw] = zsrc[row * 64 + cw];
      }
    }
    __syncthreads();
    f32x4 sa[4] = {};
#pragma unroll
    for (int ks = 0; ks < 4; ++ks) {
      f16x8 af = *(const f16x8*)&P[16 * w + lr][ks * 32 + lg * 8];
#pragma unroll
      for (int nt = 0; nt < 4; ++nt) {
        f16x8 bf = *(const f16x8*)&SMc[(nt * 16 + lr) * 136 + ks * 32 + lg * 8];
        sa[nt] = __builtin_amdgcn_mfma_f32_16x16x32_f16(af, bf, sa[nt], 0, 0, 0);
      }
    }
#pragma unroll
    for (int r = 0; r < 4; ++r) {
      const int trow = t0 + 16 * w + lg * 4 + r;
      const int pos_s = trow + kk + 1;
      float vv[4];
#pragma unroll
      for (int nt = 0; nt < 4; ++nt) vv[nt] = sa[nt][r] * 10.f;  // 1/TEMP
      float cm = fmaxf(fmaxf(vv[0], vv[1]), fmaxf(vv[2], vv[3]));
      cm = fmaxf(cm, __shfl_xor(cm, 1)); cm = fmaxf(cm, __shfl_xor(cm, 2));
      cm = fmaxf(cm, __shfl_xor(cm, 4)); cm = fmaxf(cm, __shfl_xor(cm, 8));
      const float nm = fmaxf(m_run[r], cm);
      float ps = __expf(vv[0] - nm) + __expf(vv[1] - nm) + __expf(vv[2] - nm) + __expf(vv[3] - nm);
      ps += __shfl_xor(ps, 1); ps += __shfl_xor(ps, 2); ps += __shfl_xor(ps, 4); ps += __shfl_xor(ps, 8);
      s_run[r] = s_run[r] * __expf(m_run[r] - nm) + ps;
      m_run[r] = nm;
      const int sbase = sc * 64 + lr;
#pragma unroll
      for (int nt = 0; nt < 4; ++nt) {
        const int s = sbase + nt * 16;
        if (s == pos_s) pos_v[r] = vv[nt];
        else neg_m[r] = fmaxf(neg_m[r], vv[nt]);
      }
    }
  }
  __syncthreads();
  if (t == 0) { red[0] = 0.f; red[1] = 0.f; }
  __syncthreads();
  float lsum = 0.f, csum = 0.f;
#pragma unroll
  for (int r = 0; r < 4; ++r) {
    float pv = pos_v[r], ng = neg_m[r];
    pv = fmaxf(pv, __shfl_xor(pv, 1)); pv = fmaxf(pv, __shfl_xor(pv, 2));
    pv = fmaxf(pv, __shfl_xor(pv, 4)); pv = fmaxf(pv, __shfl_xor(pv, 8));
    ng = fmaxf(ng, __shfl_xor(ng, 1)); ng = fmaxf(ng, __shfl_xor(ng, 2));
    ng = fmaxf(ng, __shfl_xor(ng, 4)); ng = fmaxf(ng, __shfl_xor(ng, 8));
    const int trow = t0 + 16 * w + lg * 4 + r;
    if (lr == 0 && trow < 244) {
      const float lse = m_run[r] + __logf(s_run[r]);
      lsum += lse - pv;
      csum += (pv >= ng) ? 1.f : 0.f;
    }
  }
  if (lr == 0) { atomicAdd(&red[0], lsum); atomicAdd(&red[1], csum); }
  __syncthreads();
  if (t == 0) { atomicAdd(&accb[0], red[0]); atomicAdd(&accb[1], red[1]); }
}

__global__ void k_fin(const float* __restrict__ accb, float* __restrict__ out) {
  out[0] = accb[0] * (1.0f / NTOT_LOSS);
  out[1] = accb[1] * (100.0f / NTOT_LOSS);
}

// ---------------------------------------------------------------------------
extern "C" void kernel_launch(void* const* d_in, const int* in_sizes, int n_in,
                              void* d_out, int out_size, void* d_ws, size_t ws_size,
                              hipStream_t stream) {
  (void)in_sizes; (void)n_in; (void)out_size; (void)ws_size;
  const float* rr  = (const float*)d_in[0];
  const float* w1  = (const float*)d_in[1];
  const float* b1  = (const float*)d_in[2];
  const float* w2  = (const float*)d_in[3];
  const float* b2  = (const float*)d_in[4];
  const float* wih = (const float*)d_in[5];
  const float* whh = (const float*)d_in[6];
  const float* bih = (const float*)d_in[7];
  const float* bhh = (const float*)d_in[8];
  const float* wkw = (const float*)d_in[9];
  const float* wkb = (const float*)d_in[10];
  float* out = (float*)d_out;
  char* ws = (char*)d_ws;

  // workspace layout
  const size_t GX_B = (size_t)32768 * 768 * 2;  // 50,331,648
  f16* gx   = (f16*)ws;
  f16* h1   = (f16*)ws;  // alias: h1 dead before gx written
  f16* zf16 = (f16*)(ws + GX_B);
  f16* cf16 = (f16*)(ws + GX_B + 8388608);
  f16* w1T  = (f16*)(ws + GX_B + 8388608 + 16777216);
  f16* w2T  = w1T + 65536;
  f16* wihF = w2T + 32768;
  uint8_t* whh8 = (uint8_t*)(wihF + 98304);     // 196608 bytes
  f16* wkT  = (f16*)(whh8 + 196608);
  float* accb = (float*)(wkT + 393216);

  float* zf32 = out + 2;
  float* cf32 = out + 2 + 4194304;

  k_prep<<<256, 256, 0, stream>>>(w1, w2, wih, whh, wkw, w1T, w2T, wihF, whh8, wkT, accb);
  k_gemm64<256, true, true><<<dim3(512, 4), 256, 0, stream>>>(rr, w1T, b1, h1, 256);
  k_enc2<<<dim3(512), 256, 0, stream>>>(h1, w2T, b2, zf32, zf16);
  k_gemm64<128, false, false><<<dim3(512, 12), 256, 0, stream>>>(zf16, wihF, bih, gx, 768);
  k_gru<<<128, 768, 0, stream>>>(gx, whh8, bhh, cf32, cf16);
  k_cpc<<<dim3(4, 128, 12), 256, 0, stream>>>(cf16, zf16, wkT, wkb, accb);
  k_fin<<<1, 1, 0, stream>>>(accb, out);
}

// Round 16
// 504.358 us; speedup vs baseline: 1.5003x; 1.5003x over previous
//
#include <hip/hip_runtime.h>
#include <stdint.h>

// ============================================================================
// CPC forward on MI355X (gfx950).
// R2-R14: W_hh residency unachievable; f16-stream floor 3072cyc/step (316us).
// R15: fp8 + inline-asm dequant REGRESSED (490us) — per-use asm serialized
// the stream (waitcnt per asm, no load clauses). Lesson: dequant must be
// builtin-native. R16: int8 W + v_dot4_i32_i8 (sdot4 builtin) — dequant is
// INSIDE the dot. Per-row absmax/127 scale; h quantized to int8 by producer
// (|h|<1 strictly). 192KB/CU/step fill = 1536cyc; VALU ~660cyc; no asm.
// Expected ~1700-2000 cyc/step -> ~190us k_gru.
// ============================================================================

typedef _Float16 f16;
typedef __attribute__((ext_vector_type(2))) _Float16 f16x2;
typedef __attribute__((ext_vector_type(8))) _Float16 f16x8;
typedef __attribute__((ext_vector_type(4))) float f32x4;

__device__ __forceinline__ f16x2 u2h(unsigned int x) { return __builtin_bit_cast(f16x2, x); }
__device__ __forceinline__ float sigm_(float x) { return __builtin_amdgcn_rcpf(1.f + __expf(-x)); }
__device__ __forceinline__ float tanh_(float x) { return 1.f - 2.f * __builtin_amdgcn_rcpf(__expf(2.f * x) + 1.f); }

#define NTOT_LOSS 374784.0f  // 12 * 128 * 244

// ---------------------------------------------------------------------------
// K0: weight conversion. W_hh -> int8 chunk-major whhQ[(jq*768+o)*16+e]
// (uint4 jq of row o = k 16jq..16jq+15, byte k-order matches h8 packing),
// per-row scale sc[o] = absmax/(127*127). Rows quantized by threads 0..767.
// ---------------------------------------------------------------------------
__global__ void k_prep(const float* __restrict__ w1, const float* __restrict__ w2,
                       const float* __restrict__ wih, const float* __restrict__ whh,
                       const float* __restrict__ wkw,
                       f16* __restrict__ w1T, f16* __restrict__ w2T, f16* __restrict__ wihF,
                       uint8_t* __restrict__ whhQ, float* __restrict__ wsc,
                       f16* __restrict__ wkT, float* __restrict__ accb) {
  const int stride = gridDim.x * blockDim.x;
  const int tid = blockIdx.x * blockDim.x + threadIdx.x;
  if (tid == 0) { accb[0] = 0.f; accb[1] = 0.f; }
  // w1 (256k x 256n) -> w1T[n][k]
  for (int i = tid; i < 65536; i += stride) { int n = i >> 8, k = i & 255; w1T[i] = (f16)w1[k * 256 + n]; }
  // w2 (256k x 128n) -> w2T[n][k]
  for (int i = tid; i < 32768; i += stride) { int n = i >> 8, k = i & 255; w2T[i] = (f16)w2[k * 128 + n]; }
  // W_ih (768 x 128) already [N][K]
  for (int i = tid; i < 98304; i += stride) wihF[i] = (f16)wih[i];
  // W_hh row quantization (thread per row)
  if (tid < 768) {
    const float* row = whh + (size_t)tid * 256;
    float amax = 0.f;
    for (int k = 0; k < 256; ++k) amax = fmaxf(amax, fabsf(row[k]));
    const float s = fmaxf(amax, 1e-20f) / 127.f;
    const float rs = 127.f / fmaxf(amax, 1e-20f);
    wsc[tid] = s / 127.f;  // combined dequant scale: s_w * (1/127 for h)
    for (int jq = 0; jq < 16; ++jq) {
      uint32_t words[4];
      for (int w32 = 0; w32 < 4; ++w32) {
        uint32_t p = 0;
        for (int e = 0; e < 4; ++e) {
          const int k = jq * 16 + w32 * 4 + e;
          const int q = (int)rintf(row[k] * rs);
          p |= ((uint32_t)(uint8_t)(int8_t)q) << (8 * e);
        }
        words[w32] = p;
      }
      *(uint4*)(whhQ + ((size_t)jq * 768 + tid) * 16) =
          make_uint4(words[0], words[1], words[2], words[3]);
    }
  }
  // Wk_w (12,256c,128d) -> wkT[kk][d][c]
  for (int i = tid; i < 393216; i += stride) {
    int kk = i >> 15, rem = i & 32767, d = rem >> 8, c = rem & 255;
    wkT[i] = (f16)wkw[(kk << 15) + c * 128 + d];
  }
}

// ---------------------------------------------------------------------------
// Generic 64x64-tile f16 MFMA GEMM (R2 version).
// ---------------------------------------------------------------------------
template <int KTOT, bool AF32, bool RELU>
__global__ __launch_bounds__(256) void k_gemm64(const void* __restrict__ Aptr,
                                                const f16* __restrict__ BT,
                                                const float* __restrict__ bias,
                                                f16* __restrict__ out, const int NT) {
  __shared__ __align__(16) f16 Al[64][40];
  __shared__ __align__(16) f16 Bl[64][40];
  const int m0 = blockIdx.x * 64;
  const int n0 = blockIdx.y * 64;
  const int t = threadIdx.x;
  const int w = t >> 6, l = t & 63, lr = l & 15, lg = l >> 4;
  const int arow = t >> 2, akq = (t & 3) * 8;
  f32x4 acc[4] = {};
  for (int ks = 0; ks < KTOT / 32; ++ks) {
    const int kc = ks * 32;
    __syncthreads();
    if constexpr (AF32) {
      const float* src = (const float*)Aptr + (size_t)(m0 + arow) * KTOT + kc + akq;
      float4 v0 = *(const float4*)src;
      float4 v1 = *(const float4*)(src + 4);
      f16x8 hv = {(f16)v0.x, (f16)v0.y, (f16)v0.z, (f16)v0.w,
                  (f16)v1.x, (f16)v1.y, (f16)v1.z, (f16)v1.w};
      *(f16x8*)&Al[arow][akq] = hv;
    } else {
      const f16* src = (const f16*)Aptr + (size_t)(m0 + arow) * KTOT + kc + akq;
      *(f16x8*)&Al[arow][akq] = *(const f16x8*)src;
    }
    *(f16x8*)&Bl[arow][akq] = *(const f16x8*)(BT + (size_t)(n0 + arow) * KTOT + kc + akq);
    __syncthreads();
    f16x8 af = *(const f16x8*)&Al[16 * w + lr][lg * 8];
#pragma unroll
    for (int nt = 0; nt < 4; ++nt) {
      f16x8 bf = *(const f16x8*)&Bl[nt * 16 + lr][lg * 8];
      acc[nt] = __builtin_amdgcn_mfma_f32_16x16x32_f16(af, bf, acc[nt], 0, 0, 0);
    }
  }
#pragma unroll
  for (int nt = 0; nt < 4; ++nt) {
    const int n = n0 + nt * 16 + lr;
    const float bb = bias[n];
#pragma unroll
    for (int r = 0; r < 4; ++r) {
      const int m = m0 + 16 * w + lg * 4 + r;
      float v = acc[nt][r] + bb;
      if (RELU) v = fmaxf(v, 0.f);
      out[(size_t)m * NT + n] = (f16)v;
    }
  }
}

// ---------------------------------------------------------------------------
// K2: z = l2norm(h1 @ w2T + b2). (R2 version)
// ---------------------------------------------------------------------------
__global__ __launch_bounds__(256) void k_enc2(const f16* __restrict__ A, const f16* __restrict__ BT,
                                              const float* __restrict__ bias,
                                              float* __restrict__ zf32, f16* __restrict__ zf16) {
  __shared__ __align__(16) f16 Al[64][40];
  __shared__ __align__(16) f16 Bl[128][40];
  const int m0 = blockIdx.x * 64;
  const int t = threadIdx.x;
  const int w = t >> 6, l = t & 63, lr = l & 15, lg = l >> 4;
  const int arow = t >> 2, akq = (t & 3) * 8;
  f32x4 acc[8] = {};
  for (int ks = 0; ks < 8; ++ks) {
    const int kc = ks * 32;
    __syncthreads();
    *(f16x8*)&Al[arow][akq] = *(const f16x8*)(A + (size_t)(m0 + arow) * 256 + kc + akq);
#pragma unroll
    for (int hh = 0; hh < 2; ++hh) {
      const int brow = arow + 64 * hh;
      *(f16x8*)&Bl[brow][akq] = *(const f16x8*)(BT + (size_t)brow * 256 + kc + akq);
    }
    __syncthreads();
    f16x8 af = *(const f16x8*)&Al[16 * w + lr][lg * 8];
#pragma unroll
    for (int nt = 0; nt < 8; ++nt) {
      f16x8 bf = *(const f16x8*)&Bl[nt * 16 + lr][lg * 8];
      acc[nt] = __builtin_amdgcn_mfma_f32_16x16x32_f16(af, bf, acc[nt], 0, 0, 0);
    }
  }
  float v[8][4];
#pragma unroll
  for (int nt = 0; nt < 8; ++nt) {
    const float bb = bias[nt * 16 + lr];
#pragma unroll
    for (int r = 0; r < 4; ++r) v[nt][r] = acc[nt][r] + bb;
  }
#pragma unroll
  for (int r = 0; r < 4; ++r) {
    float ss = 0.f;
#pragma unroll
    for (int nt = 0; nt < 8; ++nt) ss += v[nt][r] * v[nt][r];
    ss += __shfl_xor(ss, 1); ss += __shfl_xor(ss, 2); ss += __shfl_xor(ss, 4); ss += __shfl_xor(ss, 8);
    const float scl = 1.f / fmaxf(sqrtf(ss), 1e-12f);
    const int m = m0 + 16 * w + lg * 4 + r;
#pragma unroll
    for (int nt = 0; nt < 8; ++nt) {
      const int n = nt * 16 + lr;
      const float z = v[nt][r] * scl;
      zf32[(size_t)m * 128 + n] = z;
      zf16[(size_t)m * 128 + n] = (f16)z;
    }
  }
}

// ---------------------------------------------------------------------------
// K4: GRU scan, int8 W + sdot4. 128 blocks x 768 threads; thread o: gate
// g=o>>8, col c=o&255. W row = 16 uint4 int8 chunks, streamed coalesced;
// h kept as int8 in LDS (producer quantizes; |h|<1 strictly). Dequant is one
// fma at the end: dot = isum * sc[o] + b_hh. No inline asm anywhere.
// ---------------------------------------------------------------------------
__global__ __launch_bounds__(768, 3) void k_gru(const f16* __restrict__ gx, const uint8_t* __restrict__ whhQ,
                                                const float* __restrict__ wsc, const float* __restrict__ bhh,
                                                float* __restrict__ cout, f16* __restrict__ cf16) {
  __shared__ __align__(16) uint32_t h8[2][64];  // 256 int8 per buffer
  __shared__ float rz[2][256];
  const int b = blockIdx.x;
  const int o = threadIdx.x;
  const int g = o >> 8;
  const int c = o & 255;
  const float sc = wsc[o];
  const float bh = bhh[o];
  if (o < 64) { h8[0][o] = 0u; }
  float h_own = 0.f;
  const f16* gxp = gx + (size_t)b * 256 * 768 + o;
  float* coutp = cout + (size_t)b * 256 * 256 + c;
  f16* cfp = cf16 + (size_t)b * 256 * 256 + c;
  const uint8_t* wbase = whhQ + (size_t)o * 16;
  __syncthreads();
#pragma unroll 1
  for (int tt = 0; tt < 256; ++tt) {
    const int cur = tt & 1;
    const float gxv = (float)gxp[tt * 768];
    int i0 = 0, i1 = 0, i2 = 0, i3 = 0;
    const uint4* hp = (const uint4*)(&h8[cur][0]);
#pragma unroll
    for (int jq = 0; jq < 16; ++jq) {
      const uint4 wq = *(const uint4*)(wbase + (size_t)jq * 12288);  // 768*16
      const uint4 hq = hp[jq];  // wave-uniform -> LDS broadcast
      i0 = __builtin_amdgcn_sdot4((int)wq.x, (int)hq.x, i0, false);
      i1 = __builtin_amdgcn_sdot4((int)wq.y, (int)hq.y, i1, false);
      i2 = __builtin_amdgcn_sdot4((int)wq.z, (int)hq.z, i2, false);
      i3 = __builtin_amdgcn_sdot4((int)wq.w, (int)hq.w, i3, false);
    }
    const float dot = (float)((i0 + i1) + (i2 + i3)) * sc + bh;
    if (g < 2) rz[g][c] = sigm_(gxv + dot);
    __syncthreads();
    if (g == 2) {
      const float r = rz[0][c], zz = rz[1][c];
      const float n = tanh_(gxv + r * dot);
      const float hn = (1.f - zz) * n + zz * h_own;
      h_own = hn;
      const int qh = (int)rintf(hn * 127.f);
      ((uint8_t*)&h8[cur ^ 1][0])[c] = (uint8_t)(int8_t)qh;
      coutp[tt * 256] = hn;
      cfp[tt * 256] = (f16)hn;
    }
    __syncthreads();
  }
}

// ---------------------------------------------------------------------------
// K5: fused preds -> l2norm -> logits -> online LSE/pos/negmax -> loss&acc.
// (R2 version: grid (4,128,12), 256 threads, deep block queue.)
// ---------------------------------------------------------------------------
__global__ __launch_bounds__(256) void k_cpc(const f16* __restrict__ cf16, const f16* __restrict__ zf16,
                                             const f16* __restrict__ wkT, const float* __restrict__ wkb,
                                             float* __restrict__ accb) {
  __shared__ __align__(16) f16 SMc[64 * 264];   // c-tile [64][264], reused as z-chunk [64][136]
  __shared__ __align__(16) f16 Bl[128][40];
  __shared__ __align__(16) f16 P[64][136];
  __shared__ float red[2];
  const int tc = blockIdx.x, b = blockIdx.y, kk = blockIdx.z;
  const int t0 = tc * 64;
  const int t = threadIdx.x;
  const int w = t >> 6, l = t & 63, lr = l & 15, lg = l >> 4;
  {
    const uint32_t* src = (const uint32_t*)(cf16 + ((size_t)b * 256 + t0) * 256);
    uint32_t* dst = (uint32_t*)SMc;
#pragma unroll
    for (int it = 0; it < 32; ++it) {
      const int idx = it * 256 + t, row = idx >> 7, cw = idx & 127;
      dst[row * 132 + cw] = src[row * 128 + cw];
    }
  }
  f32x4 acc[8] = {};
  for (int ks = 0; ks < 8; ++ks) {
    __syncthreads();
    {
      const uint32_t* bsrc = (const uint32_t*)(wkT + ((size_t)kk << 15));
      uint32_t* bd = (uint32_t*)Bl;
#pragma unroll
      for (int it = 0; it < 8; ++it) {
        const int idx = it * 256 + t, row = idx >> 4, kw = idx & 15;
        bd[row * 20 + kw] = bsrc[row * 128 + ks * 16 + kw];
      }
    }
    __syncthreads();
    f16x8 af = *(const f16x8*)&SMc[(16 * w + lr) * 264 + ks * 32 + lg * 8];
#pragma unroll
    for (int nt = 0; nt < 8; ++nt) {
      f16x8 bf = *(const f16x8*)&Bl[nt * 16 + lr][lg * 8];
      acc[nt] = __builtin_amdgcn_mfma_f32_16x16x32_f16(af, bf, acc[nt], 0, 0, 0);
    }
  }
  {
    float v[8][4];
#pragma unroll
    for (int nt = 0; nt < 8; ++nt) {
      const float bb = wkb[kk * 128 + nt * 16 + lr];
#pragma unroll
      for (int r = 0; r < 4; ++r) v[nt][r] = acc[nt][r] + bb;
    }
#pragma unroll
    for (int r = 0; r < 4; ++r) {
      float ss = 0.f;
#pragma unroll
      for (int nt = 0; nt < 8; ++nt) ss += v[nt][r] * v[nt][r];
      ss += __shfl_xor(ss, 1); ss += __shfl_xor(ss, 2); ss += __shfl_xor(ss, 4); ss += __shfl_xor(ss, 8);
      const float scl = 1.f / fmaxf(sqrtf(ss), 1e-12f);
#pragma unroll
      for (int nt = 0; nt < 8; ++nt)
        P[16 * w + lg * 4 + r][nt * 16 + lr] = (f16)(v[nt][r] * scl);
    }
  }
  __syncthreads();
  float m_run[4], s_run[4], pos_v[4], neg_m[4];
#pragma unroll
  for (int r = 0; r < 4; ++r) { m_run[r] = -1e30f; s_run[r] = 0.f; pos_v[r] = -1e30f; neg_m[r] = -1e30f; }
  for (int sc = 0; sc < 4; ++sc) {
    __syncthreads();
    {
      const uint32_t* zsrc = (const uint32_t*)(zf16 + ((size_t)b * 256 + sc * 64) * 128);
      uint32_t* zd = (uint32_t*)SMc;
#pragma unroll
      for (int it = 0; it < 16; ++it) {
        const int idx = it * 256 + t, row = idx >> 6, cw = idx & 63;
        zd[row * 68 + cw] = zsrc[row * 64 + cw];
      }
    }
    __syncthreads();
    f32x4 sa[4] = {};
#pragma unroll
    for (int ks = 0; ks < 4; ++ks) {
      f16x8 af = *(const f16x8*)&P[16 * w + lr][ks * 32 + lg * 8];
#pragma unroll
      for (int nt = 0; nt < 4; ++nt) {
        f16x8 bf = *(const f16x8*)&SMc[(nt * 16 + lr) * 136 + ks * 32 + lg * 8];
        sa[nt] = __builtin_amdgcn_mfma_f32_16x16x32_f16(af, bf, sa[nt], 0, 0, 0);
      }
    }
#pragma unroll
    for (int r = 0; r < 4; ++r) {
      const int trow = t0 + 16 * w + lg * 4 + r;
      const int pos_s = trow + kk + 1;
      float vv[4];
#pragma unroll
      for (int nt = 0; nt < 4; ++nt) vv[nt] = sa[nt][r] * 10.f;  // 1/TEMP
      float cm = fmaxf(fmaxf(vv[0], vv[1]), fmaxf(vv[2], vv[3]));
      cm = fmaxf(cm, __shfl_xor(cm, 1)); cm = fmaxf(cm, __shfl_xor(cm, 2));
      cm = fmaxf(cm, __shfl_xor(cm, 4)); cm = fmaxf(cm, __shfl_xor(cm, 8));
      const float nm = fmaxf(m_run[r], cm);
      float ps = __expf(vv[0] - nm) + __expf(vv[1] - nm) + __expf(vv[2] - nm) + __expf(vv[3] - nm);
      ps += __shfl_xor(ps, 1); ps += __shfl_xor(ps, 2); ps += __shfl_xor(ps, 4); ps += __shfl_xor(ps, 8);
      s_run[r] = s_run[r] * __expf(m_run[r] - nm) + ps;
      m_run[r] = nm;
      const int sbase = sc * 64 + lr;
#pragma unroll
      for (int nt = 0; nt < 4; ++nt) {
        const int s = sbase + nt * 16;
        if (s == pos_s) pos_v[r] = vv[nt];
        else neg_m[r] = fmaxf(neg_m[r], vv[nt]);
      }
    }
  }
  __syncthreads();
  if (t == 0) { red[0] = 0.f; red[1] = 0.f; }
  __syncthreads();
  float lsum = 0.f, csum = 0.f;
#pragma unroll
  for (int r = 0; r < 4; ++r) {
    float pv = pos_v[r], ng = neg_m[r];
    pv = fmaxf(pv, __shfl_xor(pv, 1)); pv = fmaxf(pv, __shfl_xor(pv, 2));
    pv = fmaxf(pv, __shfl_xor(pv, 4)); pv = fmaxf(pv, __shfl_xor(pv, 8));
    ng = fmaxf(ng, __shfl_xor(ng, 1)); ng = fmaxf(ng, __shfl_xor(ng, 2));
    ng = fmaxf(ng, __shfl_xor(ng, 4)); ng = fmaxf(ng, __shfl_xor(ng, 8));
    const int trow = t0 + 16 * w + lg * 4 + r;
    if (lr == 0 && trow < 244) {
      const float lse = m_run[r] + __logf(s_run[r]);
      lsum += lse - pv;
      csum += (pv >= ng) ? 1.f : 0.f;
    }
  }
  if (lr == 0) { atomicAdd(&red[0], lsum); atomicAdd(&red[1], csum); }
  __syncthreads();
  if (t == 0) { atomicAdd(&accb[0], red[0]); atomicAdd(&accb[1], red[1]); }
}

__global__ void k_fin(const float* __restrict__ accb, float* __restrict__ out) {
  out[0] = accb[0] * (1.0f / NTOT_LOSS);
  out[1] = accb[1] * (100.0f / NTOT_LOSS);
}

// ---------------------------------------------------------------------------
extern "C" void kernel_launch(void* const* d_in, const int* in_sizes, int n_in,
                              void* d_out, int out_size, void* d_ws, size_t ws_size,
                              hipStream_t stream) {
  (void)in_sizes; (void)n_in; (void)out_size; (void)ws_size;
  const float* rr  = (const float*)d_in[0];
  const float* w1  = (const float*)d_in[1];
  const float* b1  = (const float*)d_in[2];
  const float* w2  = (const float*)d_in[3];
  const float* b2  = (const float*)d_in[4];
  const float* wih = (const float*)d_in[5];
  const float* whh = (const float*)d_in[6];
  const float* bih = (const float*)d_in[7];
  const float* bhh = (const float*)d_in[8];
  const float* wkw = (const float*)d_in[9];
  const float* wkb = (const float*)d_in[10];
  float* out = (float*)d_out;
  char* ws = (char*)d_ws;

  // workspace layout
  const size_t GX_B = (size_t)32768 * 768 * 2;  // 50,331,648
  f16* gx   = (f16*)ws;
  f16* h1   = (f16*)ws;  // alias: h1 dead before gx written
  f16* zf16 = (f16*)(ws + GX_B);
  f16* cf16 = (f16*)(ws + GX_B + 8388608);
  f16* w1T  = (f16*)(ws + GX_B + 8388608 + 16777216);
  f16* w2T  = w1T + 65536;
  f16* wihF = w2T + 32768;
  uint8_t* whhQ = (uint8_t*)(wihF + 98304);     // 196608 bytes
  float* wsc = (float*)(whhQ + 196608);         // 768 floats
  f16* wkT  = (f16*)(wsc + 768);
  float* accb = (float*)(wkT + 393216);

  float* zf32 = out + 2;
  float* cf32 = out + 2 + 4194304;

  k_prep<<<256, 256, 0, stream>>>(w1, w2, wih, whh, wkw, w1T, w2T, wihF, whhQ, wsc, wkT, accb);
  k_gemm64<256, true, true><<<dim3(512, 4), 256, 0, stream>>>(rr, w1T, b1, h1, 256);
  k_enc2<<<dim3(512), 256, 0, stream>>>(h1, w2T, b2, zf32, zf16);
  k_gemm64<128, false, false><<<dim3(512, 12), 256, 0, stream>>>(zf16, wihF, bih, gx, 768);
  k_gru<<<128, 768, 0, stream>>>(gx, whhQ, wsc, bhh, cf32, cf16);
  k_cpc<<<dim3(4, 128, 12), 256, 0, stream>>>(cf16, zf16, wkT, wkb, accb);
  k_fin<<<1, 1, 0, stream>>>(accb, out);
}

// Round 17
// 485.874 us; speedup vs baseline: 1.5573x; 1.0380x over previous
//
#include <hip/hip_runtime.h>
#include <stdint.h>

// ============================================================================
// CPC forward on MI355X (gfx950).
// R16 WIN: int8 W + sdot4 GRU (~165us). New leader: k_cpc 245us —
// latency-bound (Occ 20%, 2 blocks/CU) + 12x HBM over-fetch (FETCH 298MB,
// kk slowest in grid so c-tile re-read cold each pass).
// R17 (k_cpc only): (1) alias P onto Bl via shared char buffer (+1 barrier
// after last Bl-read MFMA) -> LDS 61.4->51.2KB -> 3 blocks/CU;
// (2) grid (kk,tc,b) with kk FASTEST -> 12 same-c-tile blocks adjacent ->
// L2 reuse, FETCH ~25-60MB.
// ============================================================================

typedef _Float16 f16;
typedef __attribute__((ext_vector_type(2))) _Float16 f16x2;
typedef __attribute__((ext_vector_type(8))) _Float16 f16x8;
typedef __attribute__((ext_vector_type(4))) float f32x4;

__device__ __forceinline__ f16x2 u2h(unsigned int x) { return __builtin_bit_cast(f16x2, x); }
__device__ __forceinline__ float sigm_(float x) { return __builtin_amdgcn_rcpf(1.f + __expf(-x)); }
__device__ __forceinline__ float tanh_(float x) { return 1.f - 2.f * __builtin_amdgcn_rcpf(__expf(2.f * x) + 1.f); }

#define NTOT_LOSS 374784.0f  // 12 * 128 * 244

// ---------------------------------------------------------------------------
// K0: weight conversion. W_hh -> int8 chunk-major + per-row scale (R16).
// ---------------------------------------------------------------------------
__global__ void k_prep(const float* __restrict__ w1, const float* __restrict__ w2,
                       const float* __restrict__ wih, const float* __restrict__ whh,
                       const float* __restrict__ wkw,
                       f16* __restrict__ w1T, f16* __restrict__ w2T, f16* __restrict__ wihF,
                       uint8_t* __restrict__ whhQ, float* __restrict__ wsc,
                       f16* __restrict__ wkT, float* __restrict__ accb) {
  const int stride = gridDim.x * blockDim.x;
  const int tid = blockIdx.x * blockDim.x + threadIdx.x;
  if (tid == 0) { accb[0] = 0.f; accb[1] = 0.f; }
  for (int i = tid; i < 65536; i += stride) { int n = i >> 8, k = i & 255; w1T[i] = (f16)w1[k * 256 + n]; }
  for (int i = tid; i < 32768; i += stride) { int n = i >> 8, k = i & 255; w2T[i] = (f16)w2[k * 128 + n]; }
  for (int i = tid; i < 98304; i += stride) wihF[i] = (f16)wih[i];
  if (tid < 768) {
    const float* row = whh + (size_t)tid * 256;
    float amax = 0.f;
    for (int k = 0; k < 256; ++k) amax = fmaxf(amax, fabsf(row[k]));
    const float s = fmaxf(amax, 1e-20f) / 127.f;
    const float rs = 127.f / fmaxf(amax, 1e-20f);
    wsc[tid] = s / 127.f;
    for (int jq = 0; jq < 16; ++jq) {
      uint32_t words[4];
      for (int w32 = 0; w32 < 4; ++w32) {
        uint32_t p = 0;
        for (int e = 0; e < 4; ++e) {
          const int k = jq * 16 + w32 * 4 + e;
          const int q = (int)rintf(row[k] * rs);
          p |= ((uint32_t)(uint8_t)(int8_t)q) << (8 * e);
        }
        words[w32] = p;
      }
      *(uint4*)(whhQ + ((size_t)jq * 768 + tid) * 16) =
          make_uint4(words[0], words[1], words[2], words[3]);
    }
  }
  for (int i = tid; i < 393216; i += stride) {
    int kk = i >> 15, rem = i & 32767, d = rem >> 8, c = rem & 255;
    wkT[i] = (f16)wkw[(kk << 15) + c * 128 + d];
  }
}

// ---------------------------------------------------------------------------
// Generic 64x64-tile f16 MFMA GEMM (R2 version).
// ---------------------------------------------------------------------------
template <int KTOT, bool AF32, bool RELU>
__global__ __launch_bounds__(256) void k_gemm64(const void* __restrict__ Aptr,
                                                const f16* __restrict__ BT,
                                                const float* __restrict__ bias,
                                                f16* __restrict__ out, const int NT) {
  __shared__ __align__(16) f16 Al[64][40];
  __shared__ __align__(16) f16 Bl[64][40];
  const int m0 = blockIdx.x * 64;
  const int n0 = blockIdx.y * 64;
  const int t = threadIdx.x;
  const int w = t >> 6, l = t & 63, lr = l & 15, lg = l >> 4;
  const int arow = t >> 2, akq = (t & 3) * 8;
  f32x4 acc[4] = {};
  for (int ks = 0; ks < KTOT / 32; ++ks) {
    const int kc = ks * 32;
    __syncthreads();
    if constexpr (AF32) {
      const float* src = (const float*)Aptr + (size_t)(m0 + arow) * KTOT + kc + akq;
      float4 v0 = *(const float4*)src;
      float4 v1 = *(const float4*)(src + 4);
      f16x8 hv = {(f16)v0.x, (f16)v0.y, (f16)v0.z, (f16)v0.w,
                  (f16)v1.x, (f16)v1.y, (f16)v1.z, (f16)v1.w};
      *(f16x8*)&Al[arow][akq] = hv;
    } else {
      const f16* src = (const f16*)Aptr + (size_t)(m0 + arow) * KTOT + kc + akq;
      *(f16x8*)&Al[arow][akq] = *(const f16x8*)src;
    }
    *(f16x8*)&Bl[arow][akq] = *(const f16x8*)(BT + (size_t)(n0 + arow) * KTOT + kc + akq);
    __syncthreads();
    f16x8 af = *(const f16x8*)&Al[16 * w + lr][lg * 8];
#pragma unroll
    for (int nt = 0; nt < 4; ++nt) {
      f16x8 bf = *(const f16x8*)&Bl[nt * 16 + lr][lg * 8];
      acc[nt] = __builtin_amdgcn_mfma_f32_16x16x32_f16(af, bf, acc[nt], 0, 0, 0);
    }
  }
#pragma unroll
  for (int nt = 0; nt < 4; ++nt) {
    const int n = n0 + nt * 16 + lr;
    const float bb = bias[n];
#pragma unroll
    for (int r = 0; r < 4; ++r) {
      const int m = m0 + 16 * w + lg * 4 + r;
      float v = acc[nt][r] + bb;
      if (RELU) v = fmaxf(v, 0.f);
      out[(size_t)m * NT + n] = (f16)v;
    }
  }
}

// ---------------------------------------------------------------------------
// K2: z = l2norm(h1 @ w2T + b2). (R2 version)
// ---------------------------------------------------------------------------
__global__ __launch_bounds__(256) void k_enc2(const f16* __restrict__ A, const f16* __restrict__ BT,
                                              const float* __restrict__ bias,
                                              float* __restrict__ zf32, f16* __restrict__ zf16) {
  __shared__ __align__(16) f16 Al[64][40];
  __shared__ __align__(16) f16 Bl[128][40];
  const int m0 = blockIdx.x * 64;
  const int t = threadIdx.x;
  const int w = t >> 6, l = t & 63, lr = l & 15, lg = l >> 4;
  const int arow = t >> 2, akq = (t & 3) * 8;
  f32x4 acc[8] = {};
  for (int ks = 0; ks < 8; ++ks) {
    const int kc = ks * 32;
    __syncthreads();
    *(f16x8*)&Al[arow][akq] = *(const f16x8*)(A + (size_t)(m0 + arow) * 256 + kc + akq);
#pragma unroll
    for (int hh = 0; hh < 2; ++hh) {
      const int brow = arow + 64 * hh;
      *(f16x8*)&Bl[brow][akq] = *(const f16x8*)(BT + (size_t)brow * 256 + kc + akq);
    }
    __syncthreads();
    f16x8 af = *(const f16x8*)&Al[16 * w + lr][lg * 8];
#pragma unroll
    for (int nt = 0; nt < 8; ++nt) {
      f16x8 bf = *(const f16x8*)&Bl[nt * 16 + lr][lg * 8];
      acc[nt] = __builtin_amdgcn_mfma_f32_16x16x32_f16(af, bf, acc[nt], 0, 0, 0);
    }
  }
  float v[8][4];
#pragma unroll
  for (int nt = 0; nt < 8; ++nt) {
    const float bb = bias[nt * 16 + lr];
#pragma unroll
    for (int r = 0; r < 4; ++r) v[nt][r] = acc[nt][r] + bb;
  }
#pragma unroll
  for (int r = 0; r < 4; ++r) {
    float ss = 0.f;
#pragma unroll
    for (int nt = 0; nt < 8; ++nt) ss += v[nt][r] * v[nt][r];
    ss += __shfl_xor(ss, 1); ss += __shfl_xor(ss, 2); ss += __shfl_xor(ss, 4); ss += __shfl_xor(ss, 8);
    const float scl = 1.f / fmaxf(sqrtf(ss), 1e-12f);
    const int m = m0 + 16 * w + lg * 4 + r;
#pragma unroll
    for (int nt = 0; nt < 8; ++nt) {
      const int n = nt * 16 + lr;
      const float z = v[nt][r] * scl;
      zf32[(size_t)m * 128 + n] = z;
      zf16[(size_t)m * 128 + n] = (f16)z;
    }
  }
}

// ---------------------------------------------------------------------------
// K4: GRU scan, int8 W + sdot4 (R16 version, unchanged).
// ---------------------------------------------------------------------------
__global__ __launch_bounds__(768, 3) void k_gru(const f16* __restrict__ gx, const uint8_t* __restrict__ whhQ,
                                                const float* __restrict__ wsc, const float* __restrict__ bhh,
                                                float* __restrict__ cout, f16* __restrict__ cf16) {
  __shared__ __align__(16) uint32_t h8[2][64];  // 256 int8 per buffer
  __shared__ float rz[2][256];
  const int b = blockIdx.x;
  const int o = threadIdx.x;
  const int g = o >> 8;
  const int c = o & 255;
  const float sc = wsc[o];
  const float bh = bhh[o];
  if (o < 64) { h8[0][o] = 0u; }
  float h_own = 0.f;
  const f16* gxp = gx + (size_t)b * 256 * 768 + o;
  float* coutp = cout + (size_t)b * 256 * 256 + c;
  f16* cfp = cf16 + (size_t)b * 256 * 256 + c;
  const uint8_t* wbase = whhQ + (size_t)o * 16;
  __syncthreads();
#pragma unroll 1
  for (int tt = 0; tt < 256; ++tt) {
    const int cur = tt & 1;
    const float gxv = (float)gxp[tt * 768];
    int i0 = 0, i1 = 0, i2 = 0, i3 = 0;
    const uint4* hp = (const uint4*)(&h8[cur][0]);
#pragma unroll
    for (int jq = 0; jq < 16; ++jq) {
      const uint4 wq = *(const uint4*)(wbase + (size_t)jq * 12288);  // 768*16
      const uint4 hq = hp[jq];  // wave-uniform -> LDS broadcast
      i0 = __builtin_amdgcn_sdot4((int)wq.x, (int)hq.x, i0, false);
      i1 = __builtin_amdgcn_sdot4((int)wq.y, (int)hq.y, i1, false);
      i2 = __builtin_amdgcn_sdot4((int)wq.z, (int)hq.z, i2, false);
      i3 = __builtin_amdgcn_sdot4((int)wq.w, (int)hq.w, i3, false);
    }
    const float dot = (float)((i0 + i1) + (i2 + i3)) * sc + bh;
    if (g < 2) rz[g][c] = sigm_(gxv + dot);
    __syncthreads();
    if (g == 2) {
      const float r = rz[0][c], zz = rz[1][c];
      const float n = tanh_(gxv + r * dot);
      const float hn = (1.f - zz) * n + zz * h_own;
      h_own = hn;
      const int qh = (int)rintf(hn * 127.f);
      ((uint8_t*)&h8[cur ^ 1][0])[c] = (uint8_t)(int8_t)qh;
      coutp[tt * 256] = hn;
      cfp[tt * 256] = (f16)hn;
    }
    __syncthreads();
  }
}

// ---------------------------------------------------------------------------
// K5: fused preds -> l2norm -> logits -> online LSE/pos/negmax -> loss&acc.
// R17: grid (kk,tc,b) kk-fastest (L2 reuse of c-tile+z across 12 kk);
// P aliased onto Bl (one 17.4KB buffer) -> LDS 51.2KB -> 3 blocks/CU.
// ---------------------------------------------------------------------------
__global__ __launch_bounds__(256) void k_cpc(const f16* __restrict__ cf16, const f16* __restrict__ zf16,
                                             const f16* __restrict__ wkT, const float* __restrict__ wkb,
                                             float* __restrict__ accb) {
  __shared__ __align__(16) f16 SMc[64 * 264];   // c-tile [64][264], reused as z-chunk [64][136]
  __shared__ __align__(16) f16 PB[64 * 136];    // Bl [128][40] (preds) then P [64][136]
  __shared__ float red[2];
  f16 (*Bl)[40] = (f16(*)[40])PB;
  f16 (*P)[136] = (f16(*)[136])PB;
  const int kk = blockIdx.x, tc = blockIdx.y, b = blockIdx.z;
  const int t0 = tc * 64;
  const int t = threadIdx.x;
  const int w = t >> 6, l = t & 63, lr = l & 15, lg = l >> 4;
  // ---- stage c tile (64 x 256 = 8192 u32) ----
  {
    const uint32_t* src = (const uint32_t*)(cf16 + ((size_t)b * 256 + t0) * 256);
    uint32_t* dst = (uint32_t*)SMc;
#pragma unroll
    for (int it = 0; it < 32; ++it) {
      const int idx = it * 256 + t, row = idx >> 7, cw = idx & 127;
      dst[row * 132 + cw] = src[row * 128 + cw];
    }
  }
  // ---- preds GEMM: (64 x 128) = c(64x256) @ Wk^T ----
  f32x4 acc[8] = {};
  for (int ks = 0; ks < 8; ++ks) {
    __syncthreads();
    {
      const uint32_t* bsrc = (const uint32_t*)(wkT + ((size_t)kk << 15));
      uint32_t* bd = (uint32_t*)PB;
#pragma unroll
      for (int it = 0; it < 8; ++it) {
        const int idx = it * 256 + t, row = idx >> 4, kw = idx & 15;
        bd[row * 20 + kw] = bsrc[row * 128 + ks * 16 + kw];
      }
    }
    __syncthreads();
    f16x8 af = *(const f16x8*)&SMc[(16 * w + lr) * 264 + ks * 32 + lg * 8];
#pragma unroll
    for (int nt = 0; nt < 8; ++nt) {
      f16x8 bf = *(const f16x8*)&Bl[nt * 16 + lr][lg * 8];
      acc[nt] = __builtin_amdgcn_mfma_f32_16x16x32_f16(af, bf, acc[nt], 0, 0, 0);
    }
  }
  __syncthreads();  // all Bl reads complete before P overwrites the buffer
  // ---- preds epilogue: bias + row l2norm -> P (aliases Bl) ----
  {
    float v[8][4];
#pragma unroll
    for (int nt = 0; nt < 8; ++nt) {
      const float bb = wkb[kk * 128 + nt * 16 + lr];
#pragma unroll
      for (int r = 0; r < 4; ++r) v[nt][r] = acc[nt][r] + bb;
    }
#pragma unroll
    for (int r = 0; r < 4; ++r) {
      float ss = 0.f;
#pragma unroll
      for (int nt = 0; nt < 8; ++nt) ss += v[nt][r] * v[nt][r];
      ss += __shfl_xor(ss, 1); ss += __shfl_xor(ss, 2); ss += __shfl_xor(ss, 4); ss += __shfl_xor(ss, 8);
      const float scl = 1.f / fmaxf(sqrtf(ss), 1e-12f);
#pragma unroll
      for (int nt = 0; nt < 8; ++nt)
        P[16 * w + lg * 4 + r][nt * 16 + lr] = (f16)(v[nt][r] * scl);
    }
  }
  __syncthreads();
  // ---- logits + online LSE/pos/negmax over 4 s-chunks ----
  float m_run[4], s_run[4], pos_v[4], neg_m[4];
#pragma unroll
  for (int r = 0; r < 4; ++r) { m_run[r] = -1e30f; s_run[r] = 0.f; pos_v[r] = -1e30f; neg_m[r] = -1e30f; }
  for (int sc = 0; sc < 4; ++sc) {
    __syncthreads();
    {
      const uint32_t* zsrc = (const uint32_t*)(zf16 + ((size_t)b * 256 + sc * 64) * 128);
      uint32_t* zd = (uint32_t*)SMc;
#pragma unroll
      for (int it = 0; it < 16; ++it) {
        const int idx = it * 256 + t, row = idx >> 6, cw = idx & 63;
        zd[row * 68 + cw] = zsrc[row * 64 + cw];
      }
    }
    __syncthreads();
    f32x4 sa[4] = {};
#pragma unroll
    for (int ks = 0; ks < 4; ++ks) {
      f16x8 af = *(const f16x8*)&P[16 * w + lr][ks * 32 + lg * 8];
#pragma unroll
      for (int nt = 0; nt < 4; ++nt) {
        f16x8 bf = *(const f16x8*)&SMc[(nt * 16 + lr) * 136 + ks * 32 + lg * 8];
        sa[nt] = __builtin_amdgcn_mfma_f32_16x16x32_f16(af, bf, sa[nt], 0, 0, 0);
      }
    }
#pragma unroll
    for (int r = 0; r < 4; ++r) {
      const int trow = t0 + 16 * w + lg * 4 + r;
      const int pos_s = trow + kk + 1;
      float vv[4];
#pragma unroll
      for (int nt = 0; nt < 4; ++nt) vv[nt] = sa[nt][r] * 10.f;  // 1/TEMP
      float cm = fmaxf(fmaxf(vv[0], vv[1]), fmaxf(vv[2], vv[3]));
      cm = fmaxf(cm, __shfl_xor(cm, 1)); cm = fmaxf(cm, __shfl_xor(cm, 2));
      cm = fmaxf(cm, __shfl_xor(cm, 4)); cm = fmaxf(cm, __shfl_xor(cm, 8));
      const float nm = fmaxf(m_run[r], cm);
      float ps = __expf(vv[0] - nm) + __expf(vv[1] - nm) + __expf(vv[2] - nm) + __expf(vv[3] - nm);
      ps += __shfl_xor(ps, 1); ps += __shfl_xor(ps, 2); ps += __shfl_xor(ps, 4); ps += __shfl_xor(ps, 8);
      s_run[r] = s_run[r] * __expf(m_run[r] - nm) + ps;
      m_run[r] = nm;
      const int sbase = sc * 64 + lr;
#pragma unroll
      for (int nt = 0; nt < 4; ++nt) {
        const int s = sbase + nt * 16;
        if (s == pos_s) pos_v[r] = vv[nt];
        else neg_m[r] = fmaxf(neg_m[r], vv[nt]);
      }
    }
  }
  __syncthreads();
  if (t == 0) { red[0] = 0.f; red[1] = 0.f; }
  __syncthreads();
  float lsum = 0.f, csum = 0.f;
#pragma unroll
  for (int r = 0; r < 4; ++r) {
    float pv = pos_v[r], ng = neg_m[r];
    pv = fmaxf(pv, __shfl_xor(pv, 1)); pv = fmaxf(pv, __shfl_xor(pv, 2));
    pv = fmaxf(pv, __shfl_xor(pv, 4)); pv = fmaxf(pv, __shfl_xor(pv, 8));
    ng = fmaxf(ng, __shfl_xor(ng, 1)); ng = fmaxf(ng, __shfl_xor(ng, 2));
    ng = fmaxf(ng, __shfl_xor(ng, 4)); ng = fmaxf(ng, __shfl_xor(ng, 8));
    const int trow = t0 + 16 * w + lg * 4 + r;
    if (lr == 0 && trow < 244) {
      const float lse = m_run[r] + __logf(s_run[r]);
      lsum += lse - pv;
      csum += (pv >= ng) ? 1.f : 0.f;
    }
  }
  if (lr == 0) { atomicAdd(&red[0], lsum); atomicAdd(&red[1], csum); }
  __syncthreads();
  if (t == 0) { atomicAdd(&accb[0], red[0]); atomicAdd(&accb[1], red[1]); }
}

__global__ void k_fin(const float* __restrict__ accb, float* __restrict__ out) {
  out[0] = accb[0] * (1.0f / NTOT_LOSS);
  out[1] = accb[1] * (100.0f / NTOT_LOSS);
}

// ---------------------------------------------------------------------------
extern "C" void kernel_launch(void* const* d_in, const int* in_sizes, int n_in,
                              void* d_out, int out_size, void* d_ws, size_t ws_size,
                              hipStream_t stream) {
  (void)in_sizes; (void)n_in; (void)out_size; (void)ws_size;
  const float* rr  = (const float*)d_in[0];
  const float* w1  = (const float*)d_in[1];
  const float* b1  = (const float*)d_in[2];
  const float* w2  = (const float*)d_in[3];
  const float* b2  = (const float*)d_in[4];
  const float* wih = (const float*)d_in[5];
  const float* whh = (const float*)d_in[6];
  const float* bih = (const float*)d_in[7];
  const float* bhh = (const float*)d_in[8];
  const float* wkw = (const float*)d_in[9];
  const float* wkb = (const float*)d_in[10];
  float* out = (float*)d_out;
  char* ws = (char*)d_ws;

  // workspace layout
  const size_t GX_B = (size_t)32768 * 768 * 2;  // 50,331,648
  f16* gx   = (f16*)ws;
  f16* h1   = (f16*)ws;  // alias: h1 dead before gx written
  f16* zf16 = (f16*)(ws + GX_B);
  f16* cf16 = (f16*)(ws + GX_B + 8388608);
  f16* w1T  = (f16*)(ws + GX_B + 8388608 + 16777216);
  f16* w2T  = w1T + 65536;
  f16* wihF = w2T + 32768;
  uint8_t* whhQ = (uint8_t*)(wihF + 98304);     // 196608 bytes
  float* wsc = (float*)(whhQ + 196608);         // 768 floats
  f16* wkT  = (f16*)(wsc + 768);
  float* accb = (float*)(wkT + 393216);

  float* zf32 = out + 2;
  float* cf32 = out + 2 + 4194304;

  k_prep<<<256, 256, 0, stream>>>(w1, w2, wih, whh, wkw, w1T, w2T, wihF, whhQ, wsc, wkT, accb);
  k_gemm64<256, true, true><<<dim3(512, 4), 256, 0, stream>>>(rr, w1T, b1, h1, 256);
  k_enc2<<<dim3(512), 256, 0, stream>>>(h1, w2T, b2, zf32, zf16);
  k_gemm64<128, false, false><<<dim3(512, 12), 256, 0, stream>>>(zf16, wihF, bih, gx, 768);
  k_gru<<<128, 768, 0, stream>>>(gx, whhQ, wsc, bhh, cf32, cf16);
  k_cpc<<<dim3(12, 4, 128), 256, 0, stream>>>(cf16, zf16, wkT, wkb, accb);
  k_fin<<<1, 1, 0, stream>>>(accb, out);
}